// Round 14
// baseline (182.410 us; speedup 1.0000x reference)
//
#include <hip/hip_runtime.h>
#include <cstdint>
#include <cstddef>

// DigitCapsules routing: B=256, R=1152, C=10, IC=8, OC=16, 3 iters.
// R14 (4 launches) = R13 structure, passes rebuilt around LINEAR u reads:
//   L1 caps_u_s1: u bf16 (94 MB) + fused pass-0 bf16 partial (R12/R13 proven).
//   L2/L3 caps_pass: NSPLIT=6 (1536 blocks). Each block STAGES its whole
//      61,440-B u-slice into LDS with one flat linear copy (15 float4/thread;
//      6-KB contiguous chunk per c; adjacent blocks = adjacent chunks), then
//      computes logits/softmax/weighted-sum from LDS (R8's proven loop).
//      Theory: the stubborn ~36 us pass = HBM at 1.1 TB/s caused by ~5000
//      concurrent 512B-granule strided streams (row-buffer thrash); linear
//      streams on this chip do 6.3 TB/s. LDS 64.6 KB -> 2 blocks/CU; DS
//      budget ~6.7 us/CU (under memory floor).
//   L4 caps_final: squash(sum 6 partials) -> out.
// Logits linear in v: b_t = u.(v1+..+v_{t-1}) -> running vsum, 1 pass/iter.
#define NB 256
#define NR 1152
#define NC 10
#define NI 8
#define NO 16
#define NSPLIT 6
#define RPB 192      // r per pass block (3 sweeps of 64)
#define NRC 144      // r-chunks in caps_u_s1 (8 r each)

static __device__ __forceinline__ uint32_t bf16_pack2(float lo, float hi) {
    uint32_t vl = __float_as_uint(lo);
    vl = vl + 0x7FFFu + ((vl >> 16) & 1u);
    uint32_t vh = __float_as_uint(hi);
    vh = vh + 0x7FFFu + ((vh >> 16) & 1u);
    return (vl >> 16) | (vh & 0xFFFF0000u);
}

// -------------------------------------------------------------------------
// caps_u_s1 (unchanged R13): 2304 blocks = 144 rc x 16 bg; 320 thr.
// W[r][c][i][oq*4..+3] = 8 float4 in regs; 16-deep b-loop; u-store uint2;
// fused s1 partial via rl-shuffle-reduce -> packed bf16 part1.
__global__ __launch_bounds__(320, 2) void caps_u_s1_kernel(
    const float* __restrict__ x, const float* __restrict__ W,
    uint32_t* __restrict__ u, uint32_t* __restrict__ part1)
{
    const int t  = threadIdx.x;
    const int c  = t >> 5;             // 0..9
    const int rl = (t & 31) >> 2;      // 0..7
    const int oq = t & 3;              // 0..3
    const int rc = blockIdx.x >> 4;    // 0..143
    const int bg = blockIdx.x & 15;    // 0..15
    const int b0 = bg * 16;
    const int r  = rc * 8 + rl;

    __shared__ float xs[16][8][8];     // 4 KB

    if (t < 256) {
        const int bi = t >> 4, rem = t & 15;
        const int rr = rem >> 1, hf = rem & 1;
        *(float4*)&xs[bi][rr][hf * 4] =
            *(const float4*)(x + ((size_t)(b0 + bi) * NR + rc * 8 + rr) * 8 + hf * 4);
    }

    const float* wb = W + ((size_t)r * NC + c) * (NI * NO) + oq * 4;
    float4 wf[8];
#pragma unroll
    for (int i = 0; i < 8; ++i) wf[i] = *(const float4*)(wb + i * NO);

    __syncthreads();

#pragma unroll 2
    for (int bi = 0; bi < 16; ++bi) {
        const float4 xv4a = *(const float4*)&xs[bi][rl][0];
        const float4 xv4b = *(const float4*)&xs[bi][rl][4];
        const float xr[8] = {xv4a.x, xv4a.y, xv4a.z, xv4a.w,
                             xv4b.x, xv4b.y, xv4b.z, xv4b.w};
        float ax = 0.f, ay = 0.f, az = 0.f, aw = 0.f;
#pragma unroll
        for (int i = 0; i < 8; ++i) {
            const float xv = xr[i];
            ax = fmaf(xv, wf[i].x, ax); ay = fmaf(xv, wf[i].y, ay);
            az = fmaf(xv, wf[i].z, az); aw = fmaf(xv, wf[i].w, aw);
        }
        uint2 s;
        s.x = bf16_pack2(ax, ay);
        s.y = bf16_pack2(az, aw);
        *(uint2*)(u + (((size_t)(b0 + bi) * NC + c) * NR + r) * 8 + oq * 2) = s;

        float sx = ax, sy = ay, sz = az, sw = aw;
#pragma unroll
        for (int off = 4; off <= 16; off <<= 1) {
            sx += __shfl_xor(sx, off); sy += __shfl_xor(sy, off);
            sz += __shfl_xor(sz, off); sw += __shfl_xor(sw, off);
        }
        if ((t & 28) == 0) {
            uint2 p;
            p.x = bf16_pack2(sx, sy);
            p.y = bf16_pack2(sz, sw);
            *(uint2*)(part1 + ((size_t)(b0 + bi) * NRC + rc) * 80
                      + c * 8 + oq * 2) = p;
        }
    }
}

// -------------------------------------------------------------------------
// prologue helper: lanes t<160 (t = c*16 + o) compute vsum1[t] =
// squash(0.1 * sum over 144 rc of bf16 part1). Deterministic.
static __device__ __forceinline__ float vsum1_col(
    const uint32_t* __restrict__ part1, const int b, const int t)
{
    const uint32_t* p = part1 + (size_t)b * NRC * 80 + (t >> 1);
    const bool hi = t & 1;
    float s0 = 0.f, s1 = 0.f, s2 = 0.f, s3 = 0.f;
#pragma unroll 4
    for (int g = 0; g < NRC; g += 4) {
        const uint32_t w0 = p[(g + 0) * 80];
        const uint32_t w1 = p[(g + 1) * 80];
        const uint32_t w2 = p[(g + 2) * 80];
        const uint32_t w3 = p[(g + 3) * 80];
        s0 += hi ? __uint_as_float(w0 & 0xFFFF0000u) : __uint_as_float(w0 << 16);
        s1 += hi ? __uint_as_float(w1 & 0xFFFF0000u) : __uint_as_float(w1 << 16);
        s2 += hi ? __uint_as_float(w2 & 0xFFFF0000u) : __uint_as_float(w2 << 16);
        s3 += hi ? __uint_as_float(w3 & 0xFFFF0000u) : __uint_as_float(w3 << 16);
    }
    const float s = 0.1f * ((s0 + s1) + (s2 + s3));
    float n2 = s * s;
    n2 += __shfl_xor(n2, 1);
    n2 += __shfl_xor(n2, 2);
    n2 += __shfl_xor(n2, 4);
    n2 += __shfl_xor(n2, 8);
    const float nrm = sqrtf(n2);
    return s * (n2 / (1.f + n2) / (nrm + 1e-8f));
}

// -------------------------------------------------------------------------
// Routing pass: block = (b, sp); 256 thr = 64 rl x 4 oq; 3 sweeps.
// Stage 61,440 B u-slice -> LDS linearly, compute from LDS.
// Prologue: vss = vsum1 (phase 1) or vsum1 + squash(sum 6 prev partials).
__global__ __launch_bounds__(256, 2) void caps_pass_kernel(
    const uint32_t* __restrict__ u, const uint32_t* __restrict__ part1,
    const float* __restrict__ part_prev, float* __restrict__ partout)
{
    const int b  = blockIdx.x / NSPLIT;
    const int sp = blockIdx.x % NSPLIT;
    const int t  = threadIdx.x;
    const int oq = t & 3;
    const int rl = t >> 2;    // 0..63

    __shared__ uint32_t lds_u[15360];   // 61,440 B: [c][192 r][8 dwords]
    __shared__ float vss[160];
    __shared__ float sred[4][160];

    // ---- linear stage: 3840 uint4 total, 15 per thread ----
    {
        const uint4* gsrc = (const uint4*)u;   // row (b,c,r) = 2 uint4
#pragma unroll
        for (int j = 0; j < 15; ++j) {
            const int f  = j * 256 + t;        // flat uint4 idx in slice
            const int c  = f / 384;            // 384 uint4 per c-chunk
            const int ro = f - c * 384;
            const uint4 v = gsrc[((size_t)(b * NC + c) * NR + sp * RPB) * 2 + ro];
            *(uint4*)&lds_u[(size_t)f * 4] = v;
        }
    }

    // ---- prologue (overlaps staging latency) ----
    if (t < 160) {
        float v = vsum1_col(part1, b, t);
        if (part_prev != nullptr) {
            float s = 0.f;
#pragma unroll
            for (int sp2 = 0; sp2 < NSPLIT; ++sp2)
                s += part_prev[((size_t)sp2 * NB + b) * 160 + t];
            float n2 = s * s;
            n2 += __shfl_xor(n2, 1);
            n2 += __shfl_xor(n2, 2);
            n2 += __shfl_xor(n2, 4);
            n2 += __shfl_xor(n2, 8);
            const float nrm = sqrtf(n2);
            v += s * (n2 / (1.f + n2) / (nrm + 1e-8f));
        }
        vss[t] = v;
    }
    __syncthreads();

    float acc[10][4];
#pragma unroll
    for (int c = 0; c < 10; ++c)
#pragma unroll
        for (int j = 0; j < 4; ++j) acc[c][j] = 0.f;

    for (int k = 0; k < 3; ++k) {
        const int r = k * 64 + rl;
        uint2 q[10];
#pragma unroll
        for (int c = 0; c < 10; ++c)
            q[c] = *(const uint2*)&lds_u[c * 1536 + r * 8 + oq * 2];

        float lg[10];
#pragma unroll
        for (int c = 0; c < 10; ++c) {
            const float4 vq = *(const float4*)&vss[c * 16 + oq * 4];
            float d = __uint_as_float(q[c].x << 16) * vq.x;
            d = fmaf(__uint_as_float(q[c].x & 0xFFFF0000u), vq.y, d);
            d = fmaf(__uint_as_float(q[c].y << 16),         vq.z, d);
            d = fmaf(__uint_as_float(q[c].y & 0xFFFF0000u), vq.w, d);
            lg[c] = d;
        }
#pragma unroll
        for (int c = 0; c < 10; ++c) {    // finish o-dot over 4 oq lanes
            lg[c] += __shfl_xor(lg[c], 1);
            lg[c] += __shfl_xor(lg[c], 2);
        }
        float m = lg[0];
#pragma unroll
        for (int c = 1; c < 10; ++c) m = fmaxf(m, lg[c]);
        float wgt[10], ssum = 0.f;
#pragma unroll
        for (int c = 0; c < 10; ++c) { wgt[c] = __expf(lg[c] - m); ssum += wgt[c]; }
        const float inv = 1.f / ssum;
#pragma unroll
        for (int c = 0; c < 10; ++c) {
            const float wv = wgt[c] * inv;
            acc[c][0] = fmaf(wv, __uint_as_float(q[c].x << 16),         acc[c][0]);
            acc[c][1] = fmaf(wv, __uint_as_float(q[c].x & 0xFFFF0000u), acc[c][1]);
            acc[c][2] = fmaf(wv, __uint_as_float(q[c].y << 16),         acc[c][2]);
            acc[c][3] = fmaf(wv, __uint_as_float(q[c].y & 0xFFFF0000u), acc[c][3]);
        }
    }

    // in-wave reduce over 16 rl-lanes (tid bits 2..5)
#pragma unroll
    for (int off = 4; off <= 32; off <<= 1)
#pragma unroll
        for (int c = 0; c < 10; ++c)
#pragma unroll
            for (int j = 0; j < 4; ++j) acc[c][j] += __shfl_xor(acc[c][j], off);

    const int wv = t >> 6;
    if ((t & 63) < 4) {
#pragma unroll
        for (int c = 0; c < 10; ++c)
#pragma unroll
            for (int j = 0; j < 4; ++j)
                sred[wv][c * 16 + oq * 4 + j] = acc[c][j];
    }
    __syncthreads();

    if (t < 160) {
        partout[((size_t)sp * NB + b) * 160 + t]
            = sred[0][t] + sred[1][t] + sred[2][t] + sred[3][t];
    }
}

// -------------------------------------------------------------------------
// final: out = squash(sum of 6 partials). grid=256 (b), 192 thr.
__global__ __launch_bounds__(192) void caps_final_kernel(
    const float* __restrict__ part2b, float* __restrict__ out)
{
    const int b = blockIdx.x;
    const int t = threadIdx.x;
    if (t >= 160) return;
    float s = 0.f;
#pragma unroll
    for (int sp = 0; sp < NSPLIT; ++sp)
        s += part2b[((size_t)sp * NB + b) * 160 + t];
    float n2 = s * s;
    n2 += __shfl_xor(n2, 1);
    n2 += __shfl_xor(n2, 2);
    n2 += __shfl_xor(n2, 4);
    n2 += __shfl_xor(n2, 8);
    const float nrm   = sqrtf(n2);
    const float scale = n2 / (1.f + n2) / (nrm + 1e-8f);
    out[(size_t)b * 160 + t] = scale * s;
}

// -------------------------------------------------------------------------
extern "C" void kernel_launch(void* const* d_in, const int* in_sizes, int n_in,
                              void* d_out, int out_size, void* d_ws, size_t ws_size,
                              hipStream_t stream) {
    const float* x = (const float*)d_in[0];   // [256,1152,8]
    const float* W = (const float*)d_in[1];   // [1,1152,10,8,16]
    float* out = (float*)d_out;               // [256,10,16]

    // ws: u 94,371,840 | part1 bf16 [256][144][80 u32] = 11,796,480
    //     p2a [6][256][160]f = 983,040 | p2b 983,040
    uint8_t*  ws   = (uint8_t*)d_ws;
    uint32_t* u    = (uint32_t*)ws;
    uint32_t* prt1 = (uint32_t*)(ws + 94371840u);
    float*    p2a  = (float*)(ws + 94371840u + 11796480u);
    float*    p2b  = (float*)(ws + 94371840u + 11796480u + 983040u);

    caps_u_s1_kernel<<<2304, 320, 0, stream>>>(x, W, u, prt1);
    caps_pass_kernel<<<NB * NSPLIT, 256, 0, stream>>>(u, prt1, nullptr, p2a);
    caps_pass_kernel<<<NB * NSPLIT, 256, 0, stream>>>(u, prt1, p2a, p2b);
    caps_final_kernel<<<NB, 192, 0, stream>>>(p2b, out);
}

// Round 15
// 139.554 us; speedup vs baseline: 1.3071x; 1.3071x over previous
//
#include <hip/hip_runtime.h>
#include <cstdint>
#include <cstddef>

// DigitCapsules routing: B=256, R=1152, C=10, IC=8, OC=16, 3 iters.
// R15 (5 launches) = R12 best-known + targeted trims:
//   L1 caps_u_s1: u bf16 (94 MB) + fused pass-0 partial -> part1 bf16
//      (11.8 MB; R13-proven numerics). No min-waves bound.
//   L2 s1_reduce: vsum = squash(0.1 * sum part1) (11.8 MB linear-ish read).
//   L3 caps_pass (pass1): R8/R12 proven shape (NSPLIT=2, 9 uint2 sweeps),
//      vss from global vsum; partials -> p2a.
//   L4 caps_pass (pass2): prologue folds vsum += squash(sum p2a) (330 KB
//      read - cheap, unlike R13's 23.6MB part1 re-read); partials -> p2b.
//   L5 caps_final: out = squash(sum p2b).
// ROOFLINE NOTE (R14 post-mortem): HBM read path ~3.15 TB/s (m13's 6.29 is
// read+write); pass at 2.62 TB/s logical w/ L3 help is ~83% of read ceiling
// -> ~36 us/pass is structural. Whole-problem floor ~130 us.
#define NB 256
#define NR 1152
#define NC 10
#define NI 8
#define NO 16
#define NSPLIT 2
#define NSWEEP 9     // r-sweeps per pass thread: 9*64 = 576 = NR/NSPLIT
#define NRC 144      // r-chunks in caps_u_s1 (8 r each)

static __device__ __forceinline__ uint32_t bf16_pack2(float lo, float hi) {
    uint32_t vl = __float_as_uint(lo);
    vl = vl + 0x7FFFu + ((vl >> 16) & 1u);
    uint32_t vh = __float_as_uint(hi);
    vh = vh + 0x7FFFu + ((vh >> 16) & 1u);
    return (vl >> 16) | (vh & 0xFFFF0000u);
}

// -------------------------------------------------------------------------
// caps_u_s1: 2304 blocks = 144 rc x 16 bg; 320 thr = c*32 + rl*4 + oq.
// W[r][c][i][oq*4..+3] = 8 float4 in regs; 16-deep b-loop; u-store uint2;
// fused s1 partial via rl-shuffle-reduce -> packed bf16 part1 (uint2).
__global__ __launch_bounds__(320) void caps_u_s1_kernel(
    const float* __restrict__ x, const float* __restrict__ W,
    uint32_t* __restrict__ u, uint32_t* __restrict__ part1)
{
    const int t  = threadIdx.x;
    const int c  = t >> 5;             // 0..9
    const int rl = (t & 31) >> 2;      // 0..7
    const int oq = t & 3;              // 0..3
    const int rc = blockIdx.x >> 4;    // 0..143
    const int bg = blockIdx.x & 15;    // 0..15
    const int b0 = bg * 16;
    const int r  = rc * 8 + rl;

    __shared__ float xs[16][8][8];     // 4 KB

    if (t < 256) {                     // 256 float4 = x[b0..+16)[rc*8..+8)[8]
        const int bi = t >> 4, rem = t & 15;
        const int rr = rem >> 1, hf = rem & 1;
        *(float4*)&xs[bi][rr][hf * 4] =
            *(const float4*)(x + ((size_t)(b0 + bi) * NR + rc * 8 + rr) * 8 + hf * 4);
    }

    const float* wb = W + ((size_t)r * NC + c) * (NI * NO) + oq * 4;
    float4 wf[8];
#pragma unroll
    for (int i = 0; i < 8; ++i) wf[i] = *(const float4*)(wb + i * NO);

    __syncthreads();

#pragma unroll 2
    for (int bi = 0; bi < 16; ++bi) {
        const float4 xv4a = *(const float4*)&xs[bi][rl][0];
        const float4 xv4b = *(const float4*)&xs[bi][rl][4];
        const float xr[8] = {xv4a.x, xv4a.y, xv4a.z, xv4a.w,
                             xv4b.x, xv4b.y, xv4b.z, xv4b.w};
        float ax = 0.f, ay = 0.f, az = 0.f, aw = 0.f;
#pragma unroll
        for (int i = 0; i < 8; ++i) {
            const float xv = xr[i];
            ax = fmaf(xv, wf[i].x, ax); ay = fmaf(xv, wf[i].y, ay);
            az = fmaf(xv, wf[i].z, az); aw = fmaf(xv, wf[i].w, aw);
        }
        uint2 s;
        s.x = bf16_pack2(ax, ay);
        s.y = bf16_pack2(az, aw);
        *(uint2*)(u + (((size_t)(b0 + bi) * NC + c) * NR + r) * 8 + oq * 2) = s;

        // fused s1 partial: reduce fp32 quad over rl (lane bits 2..4)
        float sx = ax, sy = ay, sz = az, sw = aw;
#pragma unroll
        for (int off = 4; off <= 16; off <<= 1) {
            sx += __shfl_xor(sx, off); sy += __shfl_xor(sy, off);
            sz += __shfl_xor(sz, off); sw += __shfl_xor(sw, off);
        }
        if ((t & 28) == 0) {   // rl == 0 lanes: one uint2 per (bi,c,oq)
            uint2 p;
            p.x = bf16_pack2(sx, sy);
            p.y = bf16_pack2(sz, sw);
            *(uint2*)(part1 + ((size_t)(b0 + bi) * NRC + rc) * 80
                      + c * 8 + oq * 2) = p;
        }
    }
}

// -------------------------------------------------------------------------
// s1_reduce: vsum = squash(0.1 * sum over 144 rc of bf16 part1).
// grid 256 (b), 192 thr (160 active; t = c*16 + o).
__global__ __launch_bounds__(192) void caps_s1_reduce_kernel(
    const uint32_t* __restrict__ part1, float* __restrict__ vsum)
{
    const int b = blockIdx.x;
    const int t = threadIdx.x;
    if (t >= 160) return;
    const uint32_t* p = part1 + (size_t)b * NRC * 80 + (t >> 1);
    const bool hi = t & 1;
    float s0 = 0.f, s1 = 0.f, s2 = 0.f, s3 = 0.f;
#pragma unroll 4
    for (int g = 0; g < NRC; g += 4) {
        const uint32_t w0 = p[(g + 0) * 80];
        const uint32_t w1 = p[(g + 1) * 80];
        const uint32_t w2 = p[(g + 2) * 80];
        const uint32_t w3 = p[(g + 3) * 80];
        s0 += hi ? __uint_as_float(w0 & 0xFFFF0000u) : __uint_as_float(w0 << 16);
        s1 += hi ? __uint_as_float(w1 & 0xFFFF0000u) : __uint_as_float(w1 << 16);
        s2 += hi ? __uint_as_float(w2 & 0xFFFF0000u) : __uint_as_float(w2 << 16);
        s3 += hi ? __uint_as_float(w3 & 0xFFFF0000u) : __uint_as_float(w3 << 16);
    }
    const float s = 0.1f * ((s0 + s1) + (s2 + s3));
    float n2 = s * s;
    n2 += __shfl_xor(n2, 1);
    n2 += __shfl_xor(n2, 2);
    n2 += __shfl_xor(n2, 4);
    n2 += __shfl_xor(n2, 8);
    const float nrm = sqrtf(n2);
    vsum[(size_t)b * 160 + t] = s * (n2 / (1.f + n2) / (nrm + 1e-8f));
}

// -------------------------------------------------------------------------
// Routing pass (R8/R12 proven main loop): block = (b, sp), 256 thr =
// 64 rl x 4 oq, NSWEEP=9 sweeps of uint2. Prologue: vss = vsum (pass1) or
// vsum + squash(sum part_prev) (pass2, 330 KB total read). -> partout.
__global__ __launch_bounds__(256, 2) void caps_pass_kernel(
    const uint32_t* __restrict__ u, const float* __restrict__ vsum,
    const float* __restrict__ part_prev, float* __restrict__ partout)
{
    const int b  = blockIdx.x >> 1;
    const int sp = blockIdx.x & 1;
    const int t  = threadIdx.x;
    const int oq = t & 3;
    const int rl = t >> 2;    // 0..63

    __shared__ float vss[160];
    __shared__ float sred[4][160];

    if (t < 160) {
        float v = vsum[(size_t)b * 160 + t];
        if (part_prev != nullptr) {       // pass2: add squash(s2)
            const float s = part_prev[(size_t)b * 160 + t]
                          + part_prev[((size_t)NB + b) * 160 + t];
            float n2 = s * s;
            n2 += __shfl_xor(n2, 1);
            n2 += __shfl_xor(n2, 2);
            n2 += __shfl_xor(n2, 4);
            n2 += __shfl_xor(n2, 8);
            const float nrm = sqrtf(n2);
            v += s * (n2 / (1.f + n2) / (nrm + 1e-8f));
        }
        vss[t] = v;
    }
    __syncthreads();

    float acc[10][4];
#pragma unroll
    for (int c = 0; c < 10; ++c)
#pragma unroll
        for (int j = 0; j < 4; ++j) acc[c][j] = 0.f;

    const uint2* ub = (const uint2*)u + (size_t)b * NC * NR * 4 + oq;

    for (int k = 0; k < NSWEEP; ++k) {
        const int r = sp * (NSWEEP * 64) + k * 64 + rl;
        uint2 q[10];
#pragma unroll
        for (int c = 0; c < 10; ++c) q[c] = ub[((size_t)c * NR + r) * 4];

        float lg[10];
#pragma unroll
        for (int c = 0; c < 10; ++c) {
            const float4 vq = *(const float4*)&vss[c * 16 + oq * 4];
            float d = __uint_as_float(q[c].x << 16) * vq.x;
            d = fmaf(__uint_as_float(q[c].x & 0xFFFF0000u), vq.y, d);
            d = fmaf(__uint_as_float(q[c].y << 16),         vq.z, d);
            d = fmaf(__uint_as_float(q[c].y & 0xFFFF0000u), vq.w, d);
            lg[c] = d;
        }
#pragma unroll
        for (int c = 0; c < 10; ++c) {    // finish o-dot over 4 oq lanes
            lg[c] += __shfl_xor(lg[c], 1);
            lg[c] += __shfl_xor(lg[c], 2);
        }
        float m = lg[0];
#pragma unroll
        for (int c = 1; c < 10; ++c) m = fmaxf(m, lg[c]);
        float wgt[10], ssum = 0.f;
#pragma unroll
        for (int c = 0; c < 10; ++c) { wgt[c] = __expf(lg[c] - m); ssum += wgt[c]; }
        const float inv = 1.f / ssum;
#pragma unroll
        for (int c = 0; c < 10; ++c) {
            const float wv = wgt[c] * inv;
            acc[c][0] = fmaf(wv, __uint_as_float(q[c].x << 16),         acc[c][0]);
            acc[c][1] = fmaf(wv, __uint_as_float(q[c].x & 0xFFFF0000u), acc[c][1]);
            acc[c][2] = fmaf(wv, __uint_as_float(q[c].y << 16),         acc[c][2]);
            acc[c][3] = fmaf(wv, __uint_as_float(q[c].y & 0xFFFF0000u), acc[c][3]);
        }
    }

    // in-wave reduce over 16 rl-lanes (tid bits 2..5) — once per 9 r
#pragma unroll
    for (int off = 4; off <= 32; off <<= 1)
#pragma unroll
        for (int c = 0; c < 10; ++c)
#pragma unroll
            for (int j = 0; j < 4; ++j) acc[c][j] += __shfl_xor(acc[c][j], off);

    const int wv = t >> 6;
    if ((t & 63) < 4) {
#pragma unroll
        for (int c = 0; c < 10; ++c)
#pragma unroll
            for (int j = 0; j < 4; ++j)
                sred[wv][c * 16 + oq * 4 + j] = acc[c][j];
    }
    __syncthreads();

    if (t < 160) {
        partout[((size_t)sp * NB + b) * 160 + t]
            = sred[0][t] + sred[1][t] + sred[2][t] + sred[3][t];
    }
}

// -------------------------------------------------------------------------
// final: out = squash(sum of 2 partials). grid=256 (b), 192 thr.
__global__ __launch_bounds__(192) void caps_final_kernel(
    const float* __restrict__ p2b, float* __restrict__ out)
{
    const int b = blockIdx.x;
    const int t = threadIdx.x;
    if (t >= 160) return;
    const float s = p2b[(size_t)b * 160 + t]
                  + p2b[((size_t)NB + b) * 160 + t];
    float n2 = s * s;
    n2 += __shfl_xor(n2, 1);
    n2 += __shfl_xor(n2, 2);
    n2 += __shfl_xor(n2, 4);
    n2 += __shfl_xor(n2, 8);
    const float nrm   = sqrtf(n2);
    const float scale = n2 / (1.f + n2) / (nrm + 1e-8f);
    out[(size_t)b * 160 + t] = scale * s;
}

// -------------------------------------------------------------------------
extern "C" void kernel_launch(void* const* d_in, const int* in_sizes, int n_in,
                              void* d_out, int out_size, void* d_ws, size_t ws_size,
                              hipStream_t stream) {
    const float* x = (const float*)d_in[0];   // [256,1152,8]
    const float* W = (const float*)d_in[1];   // [1,1152,10,8,16]
    float* out = (float*)d_out;               // [256,10,16]

    // ws: u 94,371,840 | part1 bf16 [256][144][80 u32] = 11,796,480
    //     p2a [2][256][160]f = 327,680 | p2b 327,680 | vsum 163,840
    uint8_t*  ws   = (uint8_t*)d_ws;
    uint32_t* u    = (uint32_t*)ws;
    uint32_t* prt1 = (uint32_t*)(ws + 94371840u);
    float*    p2a  = (float*)(ws + 94371840u + 11796480u);
    float*    p2b  = (float*)(ws + 94371840u + 11796480u + 327680u);
    float*    vsm  = (float*)(ws + 94371840u + 11796480u + 655360u);

    caps_u_s1_kernel     <<<2304, 320, 0, stream>>>(x, W, u, prt1);
    caps_s1_reduce_kernel<<<NB, 192, 0, stream>>>(prt1, vsm);
    caps_pass_kernel     <<<NB * NSPLIT, 256, 0, stream>>>(u, vsm, nullptr, p2a);
    caps_pass_kernel     <<<NB * NSPLIT, 256, 0, stream>>>(u, vsm, p2a, p2b);
    caps_final_kernel    <<<NB, 192, 0, stream>>>(p2b, out);
}

// Round 17
// 138.999 us; speedup vs baseline: 1.3123x; 1.0040x over previous
//
#include <hip/hip_runtime.h>
#include <cstdint>
#include <cstddef>

// DigitCapsules routing: B=256, R=1152, C=10, IC=8, OC=16, 3 iters.
// R17 = R15 verbatim (best passing: 139.55 us). R16's cooperative-launch
// fusion failed under harness graph capture (output never written).
//   L1 caps_u_s1: u bf16 (94 MB) + fused pass-0 partial -> part1 bf16.
//   L2 s1_reduce: vsum = squash(0.1 * sum part1).
//   L3 caps_pass (pass1): NSPLIT=2, 9 uint2 sweeps; partials -> p2a.
//   L4 caps_pass (pass2): prologue folds vsum += squash(sum p2a); -> p2b.
//   L5 caps_final: out = squash(sum p2b).
// Measured structural walls: pass u-read 2.6 TB/s logical ~ 83% of ~3.15
// TB/s read ceiling (6 variants >= 36 us); caps_u_s1 pipe-sum ~44 us;
// ~14 us = 4 launch gaps (cooperative fusion rejected by harness).
// Logits linear in v: b_t = u.(v1+..+v_{t-1}) -> running vsum, 1 pass/iter.
#define NB 256
#define NR 1152
#define NC 10
#define NI 8
#define NO 16
#define NSPLIT 2
#define NSWEEP 9     // r-sweeps per pass thread: 9*64 = 576 = NR/NSPLIT
#define NRC 144      // r-chunks in caps_u_s1 (8 r each)

static __device__ __forceinline__ uint32_t bf16_pack2(float lo, float hi) {
    uint32_t vl = __float_as_uint(lo);
    vl = vl + 0x7FFFu + ((vl >> 16) & 1u);
    uint32_t vh = __float_as_uint(hi);
    vh = vh + 0x7FFFu + ((vh >> 16) & 1u);
    return (vl >> 16) | (vh & 0xFFFF0000u);
}

// -------------------------------------------------------------------------
// caps_u_s1: 2304 blocks = 144 rc x 16 bg; 320 thr = c*32 + rl*4 + oq.
// W[r][c][i][oq*4..+3] = 8 float4 in regs; 16-deep b-loop; u-store uint2;
// fused s1 partial via rl-shuffle-reduce -> packed bf16 part1 (uint2).
__global__ __launch_bounds__(320) void caps_u_s1_kernel(
    const float* __restrict__ x, const float* __restrict__ W,
    uint32_t* __restrict__ u, uint32_t* __restrict__ part1)
{
    const int t  = threadIdx.x;
    const int c  = t >> 5;             // 0..9
    const int rl = (t & 31) >> 2;      // 0..7
    const int oq = t & 3;              // 0..3
    const int rc = blockIdx.x >> 4;    // 0..143
    const int bg = blockIdx.x & 15;    // 0..15
    const int b0 = bg * 16;
    const int r  = rc * 8 + rl;

    __shared__ float xs[16][8][8];     // 4 KB

    if (t < 256) {                     // 256 float4 = x[b0..+16)[rc*8..+8)[8]
        const int bi = t >> 4, rem = t & 15;
        const int rr = rem >> 1, hf = rem & 1;
        *(float4*)&xs[bi][rr][hf * 4] =
            *(const float4*)(x + ((size_t)(b0 + bi) * NR + rc * 8 + rr) * 8 + hf * 4);
    }

    const float* wb = W + ((size_t)r * NC + c) * (NI * NO) + oq * 4;
    float4 wf[8];
#pragma unroll
    for (int i = 0; i < 8; ++i) wf[i] = *(const float4*)(wb + i * NO);

    __syncthreads();

#pragma unroll 2
    for (int bi = 0; bi < 16; ++bi) {
        const float4 xv4a = *(const float4*)&xs[bi][rl][0];
        const float4 xv4b = *(const float4*)&xs[bi][rl][4];
        const float xr[8] = {xv4a.x, xv4a.y, xv4a.z, xv4a.w,
                             xv4b.x, xv4b.y, xv4b.z, xv4b.w};
        float ax = 0.f, ay = 0.f, az = 0.f, aw = 0.f;
#pragma unroll
        for (int i = 0; i < 8; ++i) {
            const float xv = xr[i];
            ax = fmaf(xv, wf[i].x, ax); ay = fmaf(xv, wf[i].y, ay);
            az = fmaf(xv, wf[i].z, az); aw = fmaf(xv, wf[i].w, aw);
        }
        uint2 s;
        s.x = bf16_pack2(ax, ay);
        s.y = bf16_pack2(az, aw);
        *(uint2*)(u + (((size_t)(b0 + bi) * NC + c) * NR + r) * 8 + oq * 2) = s;

        // fused s1 partial: reduce fp32 quad over rl (lane bits 2..4)
        float sx = ax, sy = ay, sz = az, sw = aw;
#pragma unroll
        for (int off = 4; off <= 16; off <<= 1) {
            sx += __shfl_xor(sx, off); sy += __shfl_xor(sy, off);
            sz += __shfl_xor(sz, off); sw += __shfl_xor(sw, off);
        }
        if ((t & 28) == 0) {   // rl == 0 lanes: one uint2 per (bi,c,oq)
            uint2 p;
            p.x = bf16_pack2(sx, sy);
            p.y = bf16_pack2(sz, sw);
            *(uint2*)(part1 + ((size_t)(b0 + bi) * NRC + rc) * 80
                      + c * 8 + oq * 2) = p;
        }
    }
}

// -------------------------------------------------------------------------
// s1_reduce: vsum = squash(0.1 * sum over 144 rc of bf16 part1).
// grid 256 (b), 192 thr (160 active; t = c*16 + o).
__global__ __launch_bounds__(192) void caps_s1_reduce_kernel(
    const uint32_t* __restrict__ part1, float* __restrict__ vsum)
{
    const int b = blockIdx.x;
    const int t = threadIdx.x;
    if (t >= 160) return;
    const uint32_t* p = part1 + (size_t)b * NRC * 80 + (t >> 1);
    const bool hi = t & 1;
    float s0 = 0.f, s1 = 0.f, s2 = 0.f, s3 = 0.f;
#pragma unroll 4
    for (int g = 0; g < NRC; g += 4) {
        const uint32_t w0 = p[(g + 0) * 80];
        const uint32_t w1 = p[(g + 1) * 80];
        const uint32_t w2 = p[(g + 2) * 80];
        const uint32_t w3 = p[(g + 3) * 80];
        s0 += hi ? __uint_as_float(w0 & 0xFFFF0000u) : __uint_as_float(w0 << 16);
        s1 += hi ? __uint_as_float(w1 & 0xFFFF0000u) : __uint_as_float(w1 << 16);
        s2 += hi ? __uint_as_float(w2 & 0xFFFF0000u) : __uint_as_float(w2 << 16);
        s3 += hi ? __uint_as_float(w3 & 0xFFFF0000u) : __uint_as_float(w3 << 16);
    }
    const float s = 0.1f * ((s0 + s1) + (s2 + s3));
    float n2 = s * s;
    n2 += __shfl_xor(n2, 1);
    n2 += __shfl_xor(n2, 2);
    n2 += __shfl_xor(n2, 4);
    n2 += __shfl_xor(n2, 8);
    const float nrm = sqrtf(n2);
    vsum[(size_t)b * 160 + t] = s * (n2 / (1.f + n2) / (nrm + 1e-8f));
}

// -------------------------------------------------------------------------
// Routing pass (R8/R12 proven main loop): block = (b, sp), 256 thr =
// 64 rl x 4 oq, NSWEEP=9 sweeps of uint2. Prologue: vss = vsum (pass1) or
// vsum + squash(sum part_prev) (pass2, 330 KB total read). -> partout.
__global__ __launch_bounds__(256, 2) void caps_pass_kernel(
    const uint32_t* __restrict__ u, const float* __restrict__ vsum,
    const float* __restrict__ part_prev, float* __restrict__ partout)
{
    const int b  = blockIdx.x >> 1;
    const int sp = blockIdx.x & 1;
    const int t  = threadIdx.x;
    const int oq = t & 3;
    const int rl = t >> 2;    // 0..63

    __shared__ float vss[160];
    __shared__ float sred[4][160];

    if (t < 160) {
        float v = vsum[(size_t)b * 160 + t];
        if (part_prev != nullptr) {       // pass2: add squash(s2)
            const float s = part_prev[(size_t)b * 160 + t]
                          + part_prev[((size_t)NB + b) * 160 + t];
            float n2 = s * s;
            n2 += __shfl_xor(n2, 1);
            n2 += __shfl_xor(n2, 2);
            n2 += __shfl_xor(n2, 4);
            n2 += __shfl_xor(n2, 8);
            const float nrm = sqrtf(n2);
            v += s * (n2 / (1.f + n2) / (nrm + 1e-8f));
        }
        vss[t] = v;
    }
    __syncthreads();

    float acc[10][4];
#pragma unroll
    for (int c = 0; c < 10; ++c)
#pragma unroll
        for (int j = 0; j < 4; ++j) acc[c][j] = 0.f;

    const uint2* ub = (const uint2*)u + (size_t)b * NC * NR * 4 + oq;

    for (int k = 0; k < NSWEEP; ++k) {
        const int r = sp * (NSWEEP * 64) + k * 64 + rl;
        uint2 q[10];
#pragma unroll
        for (int c = 0; c < 10; ++c) q[c] = ub[((size_t)c * NR + r) * 4];

        float lg[10];
#pragma unroll
        for (int c = 0; c < 10; ++c) {
            const float4 vq = *(const float4*)&vss[c * 16 + oq * 4];
            float d = __uint_as_float(q[c].x << 16) * vq.x;
            d = fmaf(__uint_as_float(q[c].x & 0xFFFF0000u), vq.y, d);
            d = fmaf(__uint_as_float(q[c].y << 16),         vq.z, d);
            d = fmaf(__uint_as_float(q[c].y & 0xFFFF0000u), vq.w, d);
            lg[c] = d;
        }
#pragma unroll
        for (int c = 0; c < 10; ++c) {    // finish o-dot over 4 oq lanes
            lg[c] += __shfl_xor(lg[c], 1);
            lg[c] += __shfl_xor(lg[c], 2);
        }
        float m = lg[0];
#pragma unroll
        for (int c = 1; c < 10; ++c) m = fmaxf(m, lg[c]);
        float wgt[10], ssum = 0.f;
#pragma unroll
        for (int c = 0; c < 10; ++c) { wgt[c] = __expf(lg[c] - m); ssum += wgt[c]; }
        const float inv = 1.f / ssum;
#pragma unroll
        for (int c = 0; c < 10; ++c) {
            const float wv = wgt[c] * inv;
            acc[c][0] = fmaf(wv, __uint_as_float(q[c].x << 16),         acc[c][0]);
            acc[c][1] = fmaf(wv, __uint_as_float(q[c].x & 0xFFFF0000u), acc[c][1]);
            acc[c][2] = fmaf(wv, __uint_as_float(q[c].y << 16),         acc[c][2]);
            acc[c][3] = fmaf(wv, __uint_as_float(q[c].y & 0xFFFF0000u), acc[c][3]);
        }
    }

    // in-wave reduce over 16 rl-lanes (tid bits 2..5) — once per 9 r
#pragma unroll
    for (int off = 4; off <= 32; off <<= 1)
#pragma unroll
        for (int c = 0; c < 10; ++c)
#pragma unroll
            for (int j = 0; j < 4; ++j) acc[c][j] += __shfl_xor(acc[c][j], off);

    const int wv = t >> 6;
    if ((t & 63) < 4) {
#pragma unroll
        for (int c = 0; c < 10; ++c)
#pragma unroll
            for (int j = 0; j < 4; ++j)
                sred[wv][c * 16 + oq * 4 + j] = acc[c][j];
    }
    __syncthreads();

    if (t < 160) {
        partout[((size_t)sp * NB + b) * 160 + t]
            = sred[0][t] + sred[1][t] + sred[2][t] + sred[3][t];
    }
}

// -------------------------------------------------------------------------
// final: out = squash(sum of 2 partials). grid=256 (b), 192 thr.
__global__ __launch_bounds__(192) void caps_final_kernel(
    const float* __restrict__ p2b, float* __restrict__ out)
{
    const int b = blockIdx.x;
    const int t = threadIdx.x;
    if (t >= 160) return;
    const float s = p2b[(size_t)b * 160 + t]
                  + p2b[((size_t)NB + b) * 160 + t];
    float n2 = s * s;
    n2 += __shfl_xor(n2, 1);
    n2 += __shfl_xor(n2, 2);
    n2 += __shfl_xor(n2, 4);
    n2 += __shfl_xor(n2, 8);
    const float nrm   = sqrtf(n2);
    const float scale = n2 / (1.f + n2) / (nrm + 1e-8f);
    out[(size_t)b * 160 + t] = scale * s;
}

// -------------------------------------------------------------------------
extern "C" void kernel_launch(void* const* d_in, const int* in_sizes, int n_in,
                              void* d_out, int out_size, void* d_ws, size_t ws_size,
                              hipStream_t stream) {
    const float* x = (const float*)d_in[0];   // [256,1152,8]
    const float* W = (const float*)d_in[1];   // [1,1152,10,8,16]
    float* out = (float*)d_out;               // [256,10,16]

    // ws: u 94,371,840 | part1 bf16 [256][144][80 u32] = 11,796,480
    //     p2a [2][256][160]f = 327,680 | p2b 327,680 | vsum 163,840
    uint8_t*  ws   = (uint8_t*)d_ws;
    uint32_t* u    = (uint32_t*)ws;
    uint32_t* prt1 = (uint32_t*)(ws + 94371840u);
    float*    p2a  = (float*)(ws + 94371840u + 11796480u);
    float*    p2b  = (float*)(ws + 94371840u + 11796480u + 327680u);
    float*    vsm  = (float*)(ws + 94371840u + 11796480u + 655360u);

    caps_u_s1_kernel     <<<2304, 320, 0, stream>>>(x, W, u, prt1);
    caps_s1_reduce_kernel<<<NB, 192, 0, stream>>>(prt1, vsm);
    caps_pass_kernel     <<<NB * NSPLIT, 256, 0, stream>>>(u, vsm, nullptr, p2a);
    caps_pass_kernel     <<<NB * NSPLIT, 256, 0, stream>>>(u, vsm, p2a, p2b);
    caps_final_kernel    <<<NB, 192, 0, stream>>>(p2b, out);
}